// Round 1
// baseline (1894.850 us; speedup 1.0000x reference)
//
#include <hip/hip_runtime.h>
#include <math.h>

#define HDIM 64
#define HF4  16   // float4 per 64-wide row

__device__ __forceinline__ void fma4(float4& a, float s, const float4 w) {
  a.x = fmaf(s, w.x, a.x);
  a.y = fmaf(s, w.y, a.y);
  a.z = fmaf(s, w.z, a.z);
  a.w = fmaf(s, w.w, a.w);
}

__device__ __forceinline__ float silu1(float v) { return __fdividef(v, 1.0f + __expf(-v)); }
__device__ __forceinline__ float tanh1(float v) {
  float t = __expf(2.0f * v);                 // t = e^{2v}
  return 1.0f - __fdividef(2.0f, t + 1.0f);   // tanh = 1 - 2/(e^{2v}+1); saturates correctly
}
__device__ __forceinline__ float4 silu4(float4 v) {
  return make_float4(silu1(v.x), silu1(v.y), silu1(v.z), silu1(v.w));
}
__device__ __forceinline__ float4 tanh4(float4 v) {
  return make_float4(tanh1(v.x), tanh1(v.y), tanh1(v.z), tanh1(v.w));
}

// Accumulate 64 k-rows (16 chunks of 4) of layer-1 for two row-vectors p0,p1.
// wbase is row-major [k][64] viewed as float4 (16 per row). fg = feature group.
__device__ __forceinline__ void seg64(float4& a0, float4& a1,
                                      const float* p0, const float* p1,
                                      const float4* wbase, int fg) {
#pragma unroll 4
  for (int kc = 0; kc < 16; ++kc) {
    float4 s0 = ((const float4*)p0)[kc];
    float4 s1 = ((const float4*)p1)[kc];
    float4 w0 = wbase[(4 * kc + 0) * HF4 + fg];
    float4 w1 = wbase[(4 * kc + 1) * HF4 + fg];
    float4 w2 = wbase[(4 * kc + 2) * HF4 + fg];
    float4 w3 = wbase[(4 * kc + 3) * HF4 + fg];
    fma4(a0, s0.x, w0); fma4(a0, s0.y, w1); fma4(a0, s0.z, w2); fma4(a0, s0.w, w3);
    fma4(a1, s1.x, w0); fma4(a1, s1.y, w1); fma4(a1, s1.z, w2); fma4(a1, s1.w, w3);
  }
}

// Layer-2 (64x64) accumulate from per-wave LDS h buffers, weights from global (L1-hot).
__device__ __forceinline__ void layer2acc(float4& o0, float4& o1,
                                          const float* h0p, const float* h1p,
                                          const float4* w2v, int fg) {
#pragma unroll 4
  for (int jc = 0; jc < 16; ++jc) {
    float4 h0 = ((const float4*)h0p)[jc];
    float4 h1 = ((const float4*)h1p)[jc];
    float4 q0 = w2v[(4 * jc + 0) * HF4 + fg];
    float4 q1 = w2v[(4 * jc + 1) * HF4 + fg];
    float4 q2 = w2v[(4 * jc + 2) * HF4 + fg];
    float4 q3 = w2v[(4 * jc + 3) * HF4 + fg];
    fma4(o0, h0.x, q0); fma4(o0, h0.y, q1); fma4(o0, h0.z, q2); fma4(o0, h0.w, q3);
    fma4(o1, h1.x, q0); fma4(o1, h1.y, q1); fma4(o1, h1.z, q2); fma4(o1, h1.w, q3);
  }
}

// ---------------- edge kernel: message MLP (state = [x_s, pe_s, x_r, pe_r, dist]) ----------------
__global__ __launch_bounds__(256, 2) void kmsg(
    const float* __restrict__ x, const float* __restrict__ pos,
    const float* __restrict__ pe, const int* __restrict__ idx32,
    const float* __restrict__ w1, const float* __restrict__ b1,
    const float* __restrict__ w2, const float* __restrict__ b2,
    float* __restrict__ aggr, int E) {
  __shared__ float4 lw1[192 * HF4];                 // 48 KB: k-rows 0..191
  __shared__ __align__(16) float lh[4][8][68];      // per-wave h scratch, 8.5 KB

  const float4* w1v = (const float4*)w1;
  for (int i = threadIdx.x; i < 192 * HF4; i += 256) lw1[i] = w1v[i];
  __syncthreads();

  const int lane = threadIdx.x & 63;
  const int wv   = threadIdx.x >> 6;
  const int fg   = lane & 15;
  const int eq   = lane >> 4;
  const int gw   = blockIdx.x * 4 + wv;
  const int stride = gridDim.x * 4 * 8;

  // int64-vs-int32 edge_index layout detection (node ids < 2^16 -> high words 0)
  const bool is64 = (idx32[1] == 0) & (idx32[3] == 0) & (idx32[5] == 0) & (idx32[7] == 0);
  const int m = is64 ? 2 : 1;

  const float4 bias1 = ((const float4*)b1)[fg];
  const float4 bias2 = ((const float4*)b2)[fg];
  const float4 wdist = w1v[256 * HF4 + fg];         // k = 256 (dist row)
  const float4* w2v  = (const float4*)w2;

  for (int base = gw * 8; base < E; base += stride) {
    const int e0 = base + eq, e1 = base + eq + 4;
    const int e0c = min(e0, E - 1), e1c = min(e1, E - 1);
    const int s0 = idx32[(size_t)m * e0c];
    const int s1 = idx32[(size_t)m * e1c];
    const int r0 = idx32[(size_t)m * (E + e0c)];
    const int r1 = idx32[(size_t)m * (E + e1c)];

    float dx = pos[3 * s0 + 0] - pos[3 * r0 + 0];
    float dy = pos[3 * s0 + 1] - pos[3 * r0 + 1];
    float dz = pos[3 * s0 + 2] - pos[3 * r0 + 2];
    const float d0 = sqrtf(dx * dx + dy * dy + dz * dz);
    dx = pos[3 * s1 + 0] - pos[3 * r1 + 0];
    dy = pos[3 * s1 + 1] - pos[3 * r1 + 1];
    dz = pos[3 * s1 + 2] - pos[3 * r1 + 2];
    const float d1 = sqrtf(dx * dx + dy * dy + dz * dz);

    float4 a0 = bias1, a1 = bias1;
    seg64(a0, a1, x  + (size_t)s0 * HDIM, x  + (size_t)s1 * HDIM, lw1,             fg); // k 0..63
    seg64(a0, a1, pe + (size_t)s0 * HDIM, pe + (size_t)s1 * HDIM, lw1 + 64 * HF4,  fg); // 64..127
    seg64(a0, a1, x  + (size_t)r0 * HDIM, x  + (size_t)r1 * HDIM, lw1 + 128 * HF4, fg); // 128..191
    seg64(a0, a1, pe + (size_t)r0 * HDIM, pe + (size_t)r1 * HDIM, w1v + 192 * HF4, fg); // 192..255 (global/L1)
    fma4(a0, d0, wdist);
    fma4(a1, d1, wdist);
    a0 = silu4(a0); a1 = silu4(a1);

    *(float4*)&lh[wv][eq][4 * fg]     = a0;   // wave-internal transpose via LDS
    *(float4*)&lh[wv][eq + 4][4 * fg] = a1;

    float4 o0 = bias2, o1 = bias2;
    layer2acc(o0, o1, &lh[wv][eq][0], &lh[wv][eq + 4][0], w2v, fg);
    o0 = silu4(o0); o1 = silu4(o1);

    if (e0 < E) {
      float* t = aggr + (size_t)r0 * HDIM + 4 * fg;
      unsafeAtomicAdd(t + 0, o0.x); unsafeAtomicAdd(t + 1, o0.y);
      unsafeAtomicAdd(t + 2, o0.z); unsafeAtomicAdd(t + 3, o0.w);
    }
    if (e1 < E) {
      float* t = aggr + (size_t)r1 * HDIM + 4 * fg;
      unsafeAtomicAdd(t + 0, o1.x); unsafeAtomicAdd(t + 1, o1.y);
      unsafeAtomicAdd(t + 2, o1.z); unsafeAtomicAdd(t + 3, o1.w);
    }
  }
}

// ---------------- edge kernel: positional MLP (state = [pe_s, pe_r, dist]) ----------------
__global__ __launch_bounds__(256, 2) void kpos(
    const float* __restrict__ pos, const float* __restrict__ pe,
    const int* __restrict__ idx32,
    const float* __restrict__ w1, const float* __restrict__ b1,
    const float* __restrict__ w2, const float* __restrict__ b2,
    float* __restrict__ aggrp, int E) {
  __shared__ float4 lw1[128 * HF4];                 // 32 KB
  __shared__ __align__(16) float lh[4][8][68];

  const float4* w1v = (const float4*)w1;
  for (int i = threadIdx.x; i < 128 * HF4; i += 256) lw1[i] = w1v[i];
  __syncthreads();

  const int lane = threadIdx.x & 63;
  const int wv   = threadIdx.x >> 6;
  const int fg   = lane & 15;
  const int eq   = lane >> 4;
  const int gw   = blockIdx.x * 4 + wv;
  const int stride = gridDim.x * 4 * 8;

  const bool is64 = (idx32[1] == 0) & (idx32[3] == 0) & (idx32[5] == 0) & (idx32[7] == 0);
  const int m = is64 ? 2 : 1;

  const float4 bias1 = ((const float4*)b1)[fg];
  const float4 bias2 = ((const float4*)b2)[fg];
  const float4 wdist = w1v[128 * HF4 + fg];         // k = 128 (dist row)
  const float4* w2v  = (const float4*)w2;

  for (int base = gw * 8; base < E; base += stride) {
    const int e0 = base + eq, e1 = base + eq + 4;
    const int e0c = min(e0, E - 1), e1c = min(e1, E - 1);
    const int s0 = idx32[(size_t)m * e0c];
    const int s1 = idx32[(size_t)m * e1c];
    const int r0 = idx32[(size_t)m * (E + e0c)];
    const int r1 = idx32[(size_t)m * (E + e1c)];

    float dx = pos[3 * s0 + 0] - pos[3 * r0 + 0];
    float dy = pos[3 * s0 + 1] - pos[3 * r0 + 1];
    float dz = pos[3 * s0 + 2] - pos[3 * r0 + 2];
    const float d0 = sqrtf(dx * dx + dy * dy + dz * dz);
    dx = pos[3 * s1 + 0] - pos[3 * r1 + 0];
    dy = pos[3 * s1 + 1] - pos[3 * r1 + 1];
    dz = pos[3 * s1 + 2] - pos[3 * r1 + 2];
    const float d1 = sqrtf(dx * dx + dy * dy + dz * dz);

    float4 a0 = bias1, a1 = bias1;
    seg64(a0, a1, pe + (size_t)s0 * HDIM, pe + (size_t)s1 * HDIM, lw1,            fg); // 0..63
    seg64(a0, a1, pe + (size_t)r0 * HDIM, pe + (size_t)r1 * HDIM, lw1 + 64 * HF4, fg); // 64..127
    fma4(a0, d0, wdist);
    fma4(a1, d1, wdist);
    a0 = tanh4(a0); a1 = tanh4(a1);

    *(float4*)&lh[wv][eq][4 * fg]     = a0;
    *(float4*)&lh[wv][eq + 4][4 * fg] = a1;

    float4 o0 = bias2, o1 = bias2;
    layer2acc(o0, o1, &lh[wv][eq][0], &lh[wv][eq + 4][0], w2v, fg);
    o0 = tanh4(o0); o1 = tanh4(o1);

    if (e0 < E) {
      float* t = aggrp + (size_t)r0 * HDIM + 4 * fg;
      unsafeAtomicAdd(t + 0, o0.x); unsafeAtomicAdd(t + 1, o0.y);
      unsafeAtomicAdd(t + 2, o0.z); unsafeAtomicAdd(t + 3, o0.w);
    }
    if (e1 < E) {
      float* t = aggrp + (size_t)r1 * HDIM + 4 * fg;
      unsafeAtomicAdd(t + 0, o1.x); unsafeAtomicAdd(t + 1, o1.y);
      unsafeAtomicAdd(t + 2, o1.z); unsafeAtomicAdd(t + 3, o1.w);
    }
  }
}

// ---------------- node kernel: update MLP ([x, pe, aggr] -> 64; NO outer activation) ----------------
// NOTE: aggr may alias outp (we read row n fully before writing row n; rows owned exclusively).
__global__ __launch_bounds__(256, 2) void knode_upd(
    const float* __restrict__ x, const float* __restrict__ pe,
    const float* aggr,
    const float* __restrict__ w1, const float* __restrict__ b1,
    const float* __restrict__ w2, const float* __restrict__ b2,
    float* outp, int N) {
  __shared__ float4 lw1[192 * HF4];                 // 48 KB
  __shared__ __align__(16) float lh[4][8][68];

  const float4* w1v = (const float4*)w1;
  for (int i = threadIdx.x; i < 192 * HF4; i += 256) lw1[i] = w1v[i];
  __syncthreads();

  const int lane = threadIdx.x & 63;
  const int wv   = threadIdx.x >> 6;
  const int fg   = lane & 15;
  const int eq   = lane >> 4;
  const int gw   = blockIdx.x * 4 + wv;
  const int stride = gridDim.x * 4 * 8;

  const float4 bias1 = ((const float4*)b1)[fg];
  const float4 bias2 = ((const float4*)b2)[fg];
  const float4* w2v  = (const float4*)w2;

  for (int base = gw * 8; base < N; base += stride) {
    const int n0 = base + eq, n1 = base + eq + 4;
    const int n0c = min(n0, N - 1), n1c = min(n1, N - 1);

    float4 a0 = bias1, a1 = bias1;
    seg64(a0, a1, x    + (size_t)n0c * HDIM, x    + (size_t)n1c * HDIM, lw1,             fg);
    seg64(a0, a1, pe   + (size_t)n0c * HDIM, pe   + (size_t)n1c * HDIM, lw1 + 64 * HF4,  fg);
    seg64(a0, a1, aggr + (size_t)n0c * HDIM, aggr + (size_t)n1c * HDIM, lw1 + 128 * HF4, fg);
    a0 = silu4(a0); a1 = silu4(a1);

    *(float4*)&lh[wv][eq][4 * fg]     = a0;
    *(float4*)&lh[wv][eq + 4][4 * fg] = a1;

    float4 o0 = bias2, o1 = bias2;
    layer2acc(o0, o1, &lh[wv][eq][0], &lh[wv][eq + 4][0], w2v, fg);
    // reference: update = silu(in@w1+b1)@w2 + b2  (no outer activation)

    if (n0 < N) *(float4*)(outp + (size_t)n0 * HDIM + 4 * fg) = o0;
    if (n1 < N) *(float4*)(outp + (size_t)n1 * HDIM + 4 * fg) = o1;
  }
}

// ---------------- node kernel: pe update MLP ([pe, aggr_pos] -> 64; tanh inner+outer) ----------------
__global__ __launch_bounds__(256, 2) void knode_upe(
    const float* __restrict__ pe,
    const float* aggrp,
    const float* __restrict__ w1, const float* __restrict__ b1,
    const float* __restrict__ w2, const float* __restrict__ b2,
    float* outp, int N) {
  __shared__ float4 lw1[128 * HF4];                 // 32 KB
  __shared__ __align__(16) float lh[4][8][68];

  const float4* w1v = (const float4*)w1;
  for (int i = threadIdx.x; i < 128 * HF4; i += 256) lw1[i] = w1v[i];
  __syncthreads();

  const int lane = threadIdx.x & 63;
  const int wv   = threadIdx.x >> 6;
  const int fg   = lane & 15;
  const int eq   = lane >> 4;
  const int gw   = blockIdx.x * 4 + wv;
  const int stride = gridDim.x * 4 * 8;

  const float4 bias1 = ((const float4*)b1)[fg];
  const float4 bias2 = ((const float4*)b2)[fg];
  const float4* w2v  = (const float4*)w2;

  for (int base = gw * 8; base < N; base += stride) {
    const int n0 = base + eq, n1 = base + eq + 4;
    const int n0c = min(n0, N - 1), n1c = min(n1, N - 1);

    float4 a0 = bias1, a1 = bias1;
    seg64(a0, a1, pe    + (size_t)n0c * HDIM, pe    + (size_t)n1c * HDIM, lw1,            fg);
    seg64(a0, a1, aggrp + (size_t)n0c * HDIM, aggrp + (size_t)n1c * HDIM, lw1 + 64 * HF4, fg);
    a0 = tanh4(a0); a1 = tanh4(a1);

    *(float4*)&lh[wv][eq][4 * fg]     = a0;
    *(float4*)&lh[wv][eq + 4][4 * fg] = a1;

    float4 o0 = bias2, o1 = bias2;
    layer2acc(o0, o1, &lh[wv][eq][0], &lh[wv][eq + 4][0], w2v, fg);
    o0 = tanh4(o0); o1 = tanh4(o1);

    if (n0 < N) *(float4*)(outp + (size_t)n0 * HDIM + 4 * fg) = o0;
    if (n1 < N) *(float4*)(outp + (size_t)n1 * HDIM + 4 * fg) = o1;
  }
}

extern "C" void kernel_launch(void* const* d_in, const int* in_sizes, int n_in,
                              void* d_out, int out_size, void* d_ws, size_t ws_size,
                              hipStream_t stream) {
  const float* x    = (const float*)d_in[0];
  const float* pos  = (const float*)d_in[1];
  const float* pe   = (const float*)d_in[2];
  const int*   eidx = (const int*)d_in[3];
  const float* msg_w1  = (const float*)d_in[4];
  const float* msg_b1  = (const float*)d_in[5];
  const float* msg_w2  = (const float*)d_in[6];
  const float* msg_b2  = (const float*)d_in[7];
  const float* mpos_w1 = (const float*)d_in[8];
  const float* mpos_b1 = (const float*)d_in[9];
  const float* mpos_w2 = (const float*)d_in[10];
  const float* mpos_b2 = (const float*)d_in[11];
  const float* upd_w1  = (const float*)d_in[12];
  const float* upd_b1  = (const float*)d_in[13];
  const float* upd_w2  = (const float*)d_in[14];
  const float* upd_b2  = (const float*)d_in[15];
  const float* upe_w1  = (const float*)d_in[16];
  const float* upe_b1  = (const float*)d_in[17];
  const float* upe_w2  = (const float*)d_in[18];
  const float* upe_b2  = (const float*)d_in[19];

  const int N = in_sizes[0] / HDIM;
  const int E = in_sizes[3] / 2;

  float* out_upd = (float*)d_out;                       // also used as aggr accumulator
  float* out_upe = out_upd + (size_t)N * HDIM;          // also used as aggr_pos accumulator

  // zero accumulators (d_out is poisoned before every timed launch)
  hipMemsetAsync(d_out, 0, (size_t)2 * N * HDIM * sizeof(float), stream);

  kmsg<<<512, 256, 0, stream>>>(x, pos, pe, eidx, msg_w1, msg_b1, msg_w2, msg_b2, out_upd, E);
  kpos<<<768, 256, 0, stream>>>(pos, pe, eidx, mpos_w1, mpos_b1, mpos_w2, mpos_b2, out_upe, E);
  knode_upd<<<512, 256, 0, stream>>>(x, pe, out_upd, upd_w1, upd_b1, upd_w2, upd_b2, out_upd, N);
  knode_upe<<<768, 256, 0, stream>>>(pe, out_upe, upe_w1, upe_b1, upe_w2, upe_b2, out_upe, N);
}

// Round 2
// 1866.385 us; speedup vs baseline: 1.0153x; 1.0153x over previous
//
#include <hip/hip_runtime.h>
#include <math.h>

#define HDIM 64
#define HF4  16   // float4 per 64-wide row

__device__ __forceinline__ void fma4(float4& a, float s, const float4 w) {
  a.x = fmaf(s, w.x, a.x);
  a.y = fmaf(s, w.y, a.y);
  a.z = fmaf(s, w.z, a.z);
  a.w = fmaf(s, w.w, a.w);
}

__device__ __forceinline__ float silu1(float v) { return __fdividef(v, 1.0f + __expf(-v)); }
__device__ __forceinline__ float tanh1(float v) {
  float t = __expf(2.0f * v);
  return 1.0f - __fdividef(2.0f, t + 1.0f);
}
__device__ __forceinline__ float4 silu4(float4 v) {
  return make_float4(silu1(v.x), silu1(v.y), silu1(v.z), silu1(v.w));
}
__device__ __forceinline__ float4 tanh4(float4 v) {
  return make_float4(tanh1(v.x), tanh1(v.y), tanh1(v.z), tanh1(v.w));
}

// ---- 8-edge layer-1 segment: 64 k-rows of weights (wb), 8 gathered source rows ----
// Each weight float4 read is amortized over 8 edges (vs 2 before): LDS-pipe load /4.
__device__ __forceinline__ void seg64x8(float4 a[8], const float4* __restrict__ srcv,
                                        const int o[8], const float4* __restrict__ wb,
                                        int fg) {
#pragma unroll 4
  for (int kc = 0; kc < 16; ++kc) {
    float4 s[8];
#pragma unroll
    for (int e = 0; e < 8; ++e) s[e] = srcv[o[e] + kc];
    float4 w0 = wb[(4 * kc + 0) * HF4 + fg];
    float4 w1 = wb[(4 * kc + 1) * HF4 + fg];
    float4 w2 = wb[(4 * kc + 2) * HF4 + fg];
    float4 w3 = wb[(4 * kc + 3) * HF4 + fg];
#pragma unroll
    for (int e = 0; e < 8; ++e) {
      fma4(a[e], s[e].x, w0); fma4(a[e], s[e].y, w1);
      fma4(a[e], s[e].z, w2); fma4(a[e], s[e].w, w3);
    }
  }
}

// ---- layer-2 for 4 edges: h rows from per-wave LDS scratch, weights from global (L1-hot) ----
__device__ __forceinline__ void l2x4(float4 o4[4], const float* __restrict__ hb, int eq,
                                     const float4* __restrict__ w2v, int fg) {
#pragma unroll 4
  for (int jc = 0; jc < 16; ++jc) {
    float4 q0 = w2v[(4 * jc + 0) * HF4 + fg];
    float4 q1 = w2v[(4 * jc + 1) * HF4 + fg];
    float4 q2 = w2v[(4 * jc + 2) * HF4 + fg];
    float4 q3 = w2v[(4 * jc + 3) * HF4 + fg];
#pragma unroll
    for (int ii = 0; ii < 4; ++ii) {
      float4 h = *(const float4*)(hb + (eq + 4 * ii) * 68 + 4 * jc);
      fma4(o4[ii], h.x, q0); fma4(o4[ii], h.y, q1);
      fma4(o4[ii], h.z, q2); fma4(o4[ii], h.w, q3);
    }
  }
}

// 2-accumulator variants for the small node kernels (unchanged structure from R1)
__device__ __forceinline__ void seg64(float4& a0, float4& a1,
                                      const float* p0, const float* p1,
                                      const float4* wbase, int fg) {
#pragma unroll 4
  for (int kc = 0; kc < 16; ++kc) {
    float4 s0 = ((const float4*)p0)[kc];
    float4 s1 = ((const float4*)p1)[kc];
    float4 w0 = wbase[(4 * kc + 0) * HF4 + fg];
    float4 w1 = wbase[(4 * kc + 1) * HF4 + fg];
    float4 w2 = wbase[(4 * kc + 2) * HF4 + fg];
    float4 w3 = wbase[(4 * kc + 3) * HF4 + fg];
    fma4(a0, s0.x, w0); fma4(a0, s0.y, w1); fma4(a0, s0.z, w2); fma4(a0, s0.w, w3);
    fma4(a1, s1.x, w0); fma4(a1, s1.y, w1); fma4(a1, s1.z, w2); fma4(a1, s1.w, w3);
  }
}

__device__ __forceinline__ void layer2acc(float4& o0, float4& o1,
                                          const float* h0p, const float* h1p,
                                          const float4* w2v, int fg) {
#pragma unroll 4
  for (int jc = 0; jc < 16; ++jc) {
    float4 h0 = ((const float4*)h0p)[jc];
    float4 h1 = ((const float4*)h1p)[jc];
    float4 q0 = w2v[(4 * jc + 0) * HF4 + fg];
    float4 q1 = w2v[(4 * jc + 1) * HF4 + fg];
    float4 q2 = w2v[(4 * jc + 2) * HF4 + fg];
    float4 q3 = w2v[(4 * jc + 3) * HF4 + fg];
    fma4(o0, h0.x, q0); fma4(o0, h0.y, q1); fma4(o0, h0.z, q2); fma4(o0, h0.w, q3);
    fma4(o1, h1.x, q0); fma4(o1, h1.y, q1); fma4(o1, h1.z, q2); fma4(o1, h1.w, q3);
  }
}

// ---------------- edge kernel: message MLP (state = [x_s, pe_s, x_r, pe_r, dist]) ----------------
__global__ __launch_bounds__(256, 2) void kmsg(
    const float* __restrict__ x, const float* __restrict__ pos,
    const float* __restrict__ pe, const int* __restrict__ idx32,
    const float* __restrict__ w1, const float* __restrict__ b1,
    const float* __restrict__ w2, const float* __restrict__ b2,
    float* __restrict__ aggr, int E) {
  __shared__ float4 lw1[192 * HF4];                 // 48 KB: k-rows 0..191
  __shared__ __align__(16) float lh[4][16][68];     // per-wave h scratch, 17.4 KB

  const float4* w1v = (const float4*)w1;
  for (int i = threadIdx.x; i < 192 * HF4; i += 256) lw1[i] = w1v[i];
  __syncthreads();

  const int lane = threadIdx.x & 63;
  const int wv   = threadIdx.x >> 6;
  const int fg   = lane & 15;
  const int eq   = lane >> 4;
  const int gw   = blockIdx.x * 4 + wv;
  const int stride = gridDim.x * 4 * 32;

  const bool is64 = (idx32[1] == 0) & (idx32[3] == 0) & (idx32[5] == 0) & (idx32[7] == 0);
  const int m = is64 ? 2 : 1;

  const float4 bias1 = ((const float4*)b1)[fg];
  const float4 bias2 = ((const float4*)b2)[fg];
  const float4 wdist = w1v[256 * HF4 + fg];         // k = 256 (dist row)
  const float4* w2v  = (const float4*)w2;
  const float4* w1g  = w1v + 192 * HF4;             // rows 192..255 stay in global/L1
  const float4* xv   = (const float4*)x;
  const float4* pev  = (const float4*)pe;
  float* hb = &lh[wv][0][0];

  for (int base = gw * 32; base < E; base += stride) {
    int o_s[8], o_r[8];
    float4 a[8];
#pragma unroll
    for (int i = 0; i < 8; ++i) {
      const int e  = base + eq + 4 * i;
      const int ec = min(e, E - 1);
      const int s  = idx32[(size_t)m * ec];
      const int r  = idx32[(size_t)m * (E + ec)];
      o_s[i] = s * 16; o_r[i] = r * 16;
      const float dx = pos[3 * s + 0] - pos[3 * r + 0];
      const float dy = pos[3 * s + 1] - pos[3 * r + 1];
      const float dz = pos[3 * s + 2] - pos[3 * r + 2];
      const float dd = sqrtf(dx * dx + dy * dy + dz * dz);
      a[i] = bias1;
      fma4(a[i], dd, wdist);          // fold dist row in now; frees dd immediately
    }

    seg64x8(a, xv,  o_s, lw1,             fg);  // k   0..63   x[send]
    seg64x8(a, pev, o_s, lw1 +  64 * HF4, fg);  // k  64..127  pe[send]
    seg64x8(a, xv,  o_r, lw1 + 128 * HF4, fg);  // k 128..191  x[rec]
    seg64x8(a, pev, o_r, w1g,             fg);  // k 192..255  pe[rec] (weights from L1)

#pragma unroll
    for (int i = 0; i < 8; ++i) a[i] = silu4(a[i]);

#pragma unroll
    for (int p = 0; p < 2; ++p) {
      // wave-internal transpose via LDS (16 edges per pass)
#pragma unroll
      for (int ii = 0; ii < 4; ++ii)
        *(float4*)(hb + (eq + 4 * ii) * 68 + 4 * fg) = a[4 * p + ii];

      float4 o4[4] = {bias2, bias2, bias2, bias2};
      l2x4(o4, hb, eq, w2v, fg);

#pragma unroll
      for (int ii = 0; ii < 4; ++ii) {
        const int i = 4 * p + ii;
        const int e = base + eq + 4 * i;
        if (e < E) {
          float4 ov = silu4(o4[ii]);
          float* t = aggr + (size_t)o_r[i] * 4 + 4 * fg;
          unsafeAtomicAdd(t + 0, ov.x); unsafeAtomicAdd(t + 1, ov.y);
          unsafeAtomicAdd(t + 2, ov.z); unsafeAtomicAdd(t + 3, ov.w);
        }
      }
    }
  }
}

// ---------------- edge kernel: positional MLP (state = [pe_s, pe_r, dist]) ----------------
__global__ __launch_bounds__(256, 2) void kpos(
    const float* __restrict__ pos, const float* __restrict__ pe,
    const int* __restrict__ idx32,
    const float* __restrict__ w1, const float* __restrict__ b1,
    const float* __restrict__ w2, const float* __restrict__ b2,
    float* __restrict__ aggrp, int E) {
  __shared__ float4 lw1[128 * HF4];                 // 32 KB
  __shared__ __align__(16) float lh[4][16][68];

  const float4* w1v = (const float4*)w1;
  for (int i = threadIdx.x; i < 128 * HF4; i += 256) lw1[i] = w1v[i];
  __syncthreads();

  const int lane = threadIdx.x & 63;
  const int wv   = threadIdx.x >> 6;
  const int fg   = lane & 15;
  const int eq   = lane >> 4;
  const int gw   = blockIdx.x * 4 + wv;
  const int stride = gridDim.x * 4 * 32;

  const bool is64 = (idx32[1] == 0) & (idx32[3] == 0) & (idx32[5] == 0) & (idx32[7] == 0);
  const int m = is64 ? 2 : 1;

  const float4 bias1 = ((const float4*)b1)[fg];
  const float4 bias2 = ((const float4*)b2)[fg];
  const float4 wdist = w1v[128 * HF4 + fg];         // k = 128 (dist row)
  const float4* w2v  = (const float4*)w2;
  const float4* pev  = (const float4*)pe;
  float* hb = &lh[wv][0][0];

  for (int base = gw * 32; base < E; base += stride) {
    int o_s[8], o_r[8];
    float4 a[8];
#pragma unroll
    for (int i = 0; i < 8; ++i) {
      const int e  = base + eq + 4 * i;
      const int ec = min(e, E - 1);
      const int s  = idx32[(size_t)m * ec];
      const int r  = idx32[(size_t)m * (E + ec)];
      o_s[i] = s * 16; o_r[i] = r * 16;
      const float dx = pos[3 * s + 0] - pos[3 * r + 0];
      const float dy = pos[3 * s + 1] - pos[3 * r + 1];
      const float dz = pos[3 * s + 2] - pos[3 * r + 2];
      const float dd = sqrtf(dx * dx + dy * dy + dz * dz);
      a[i] = bias1;
      fma4(a[i], dd, wdist);
    }

    seg64x8(a, pev, o_s, lw1,            fg);  // k  0..63   pe[send]
    seg64x8(a, pev, o_r, lw1 + 64 * HF4, fg);  // k 64..127  pe[rec]

#pragma unroll
    for (int i = 0; i < 8; ++i) a[i] = tanh4(a[i]);

#pragma unroll
    for (int p = 0; p < 2; ++p) {
#pragma unroll
      for (int ii = 0; ii < 4; ++ii)
        *(float4*)(hb + (eq + 4 * ii) * 68 + 4 * fg) = a[4 * p + ii];

      float4 o4[4] = {bias2, bias2, bias2, bias2};
      l2x4(o4, hb, eq, w2v, fg);

#pragma unroll
      for (int ii = 0; ii < 4; ++ii) {
        const int i = 4 * p + ii;
        const int e = base + eq + 4 * i;
        if (e < E) {
          float4 ov = tanh4(o4[ii]);
          float* t = aggrp + (size_t)o_r[i] * 4 + 4 * fg;
          unsafeAtomicAdd(t + 0, ov.x); unsafeAtomicAdd(t + 1, ov.y);
          unsafeAtomicAdd(t + 2, ov.z); unsafeAtomicAdd(t + 3, ov.w);
        }
      }
    }
  }
}

// ---------------- node kernel: update MLP ([x, pe, aggr] -> 64; NO outer activation) ----------------
__global__ __launch_bounds__(256, 2) void knode_upd(
    const float* __restrict__ x, const float* __restrict__ pe,
    const float* aggr,
    const float* __restrict__ w1, const float* __restrict__ b1,
    const float* __restrict__ w2, const float* __restrict__ b2,
    float* outp, int N) {
  __shared__ float4 lw1[192 * HF4];
  __shared__ __align__(16) float lh[4][8][68];

  const float4* w1v = (const float4*)w1;
  for (int i = threadIdx.x; i < 192 * HF4; i += 256) lw1[i] = w1v[i];
  __syncthreads();

  const int lane = threadIdx.x & 63;
  const int wv   = threadIdx.x >> 6;
  const int fg   = lane & 15;
  const int eq   = lane >> 4;
  const int gw   = blockIdx.x * 4 + wv;
  const int stride = gridDim.x * 4 * 8;

  const float4 bias1 = ((const float4*)b1)[fg];
  const float4 bias2 = ((const float4*)b2)[fg];
  const float4* w2v  = (const float4*)w2;

  for (int base = gw * 8; base < N; base += stride) {
    const int n0 = base + eq, n1 = base + eq + 4;
    const int n0c = min(n0, N - 1), n1c = min(n1, N - 1);

    float4 a0 = bias1, a1 = bias1;
    seg64(a0, a1, x    + (size_t)n0c * HDIM, x    + (size_t)n1c * HDIM, lw1,             fg);
    seg64(a0, a1, pe   + (size_t)n0c * HDIM, pe   + (size_t)n1c * HDIM, lw1 + 64 * HF4,  fg);
    seg64(a0, a1, aggr + (size_t)n0c * HDIM, aggr + (size_t)n1c * HDIM, lw1 + 128 * HF4, fg);
    a0 = silu4(a0); a1 = silu4(a1);

    *(float4*)&lh[wv][eq][4 * fg]     = a0;
    *(float4*)&lh[wv][eq + 4][4 * fg] = a1;

    float4 o0 = bias2, o1 = bias2;
    layer2acc(o0, o1, &lh[wv][eq][0], &lh[wv][eq + 4][0], w2v, fg);

    if (n0 < N) *(float4*)(outp + (size_t)n0 * HDIM + 4 * fg) = o0;
    if (n1 < N) *(float4*)(outp + (size_t)n1 * HDIM + 4 * fg) = o1;
  }
}

// ---------------- node kernel: pe update MLP ([pe, aggr_pos] -> 64; tanh inner+outer) ----------------
__global__ __launch_bounds__(256, 2) void knode_upe(
    const float* __restrict__ pe,
    const float* aggrp,
    const float* __restrict__ w1, const float* __restrict__ b1,
    const float* __restrict__ w2, const float* __restrict__ b2,
    float* outp, int N) {
  __shared__ float4 lw1[128 * HF4];
  __shared__ __align__(16) float lh[4][8][68];

  const float4* w1v = (const float4*)w1;
  for (int i = threadIdx.x; i < 128 * HF4; i += 256) lw1[i] = w1v[i];
  __syncthreads();

  const int lane = threadIdx.x & 63;
  const int wv   = threadIdx.x >> 6;
  const int fg   = lane & 15;
  const int eq   = lane >> 4;
  const int gw   = blockIdx.x * 4 + wv;
  const int stride = gridDim.x * 4 * 8;

  const float4 bias1 = ((const float4*)b1)[fg];
  const float4 bias2 = ((const float4*)b2)[fg];
  const float4* w2v  = (const float4*)w2;

  for (int base = gw * 8; base < N; base += stride) {
    const int n0 = base + eq, n1 = base + eq + 4;
    const int n0c = min(n0, N - 1), n1c = min(n1, N - 1);

    float4 a0 = bias1, a1 = bias1;
    seg64(a0, a1, pe    + (size_t)n0c * HDIM, pe    + (size_t)n1c * HDIM, lw1,            fg);
    seg64(a0, a1, aggrp + (size_t)n0c * HDIM, aggrp + (size_t)n1c * HDIM, lw1 + 64 * HF4, fg);
    a0 = tanh4(a0); a1 = tanh4(a1);

    *(float4*)&lh[wv][eq][4 * fg]     = a0;
    *(float4*)&lh[wv][eq + 4][4 * fg] = a1;

    float4 o0 = bias2, o1 = bias2;
    layer2acc(o0, o1, &lh[wv][eq][0], &lh[wv][eq + 4][0], w2v, fg);
    o0 = tanh4(o0); o1 = tanh4(o1);

    if (n0 < N) *(float4*)(outp + (size_t)n0 * HDIM + 4 * fg) = o0;
    if (n1 < N) *(float4*)(outp + (size_t)n1 * HDIM + 4 * fg) = o1;
  }
}

extern "C" void kernel_launch(void* const* d_in, const int* in_sizes, int n_in,
                              void* d_out, int out_size, void* d_ws, size_t ws_size,
                              hipStream_t stream) {
  const float* x    = (const float*)d_in[0];
  const float* pos  = (const float*)d_in[1];
  const float* pe   = (const float*)d_in[2];
  const int*   eidx = (const int*)d_in[3];
  const float* msg_w1  = (const float*)d_in[4];
  const float* msg_b1  = (const float*)d_in[5];
  const float* msg_w2  = (const float*)d_in[6];
  const float* msg_b2  = (const float*)d_in[7];
  const float* mpos_w1 = (const float*)d_in[8];
  const float* mpos_b1 = (const float*)d_in[9];
  const float* mpos_w2 = (const float*)d_in[10];
  const float* mpos_b2 = (const float*)d_in[11];
  const float* upd_w1  = (const float*)d_in[12];
  const float* upd_b1  = (const float*)d_in[13];
  const float* upd_w2  = (const float*)d_in[14];
  const float* upd_b2  = (const float*)d_in[15];
  const float* upe_w1  = (const float*)d_in[16];
  const float* upe_b1  = (const float*)d_in[17];
  const float* upe_w2  = (const float*)d_in[18];
  const float* upe_b2  = (const float*)d_in[19];

  const int N = in_sizes[0] / HDIM;
  const int E = in_sizes[3] / 2;

  float* out_upd = (float*)d_out;                       // also aggr accumulator
  float* out_upe = out_upd + (size_t)N * HDIM;          // also aggr_pos accumulator

  hipMemsetAsync(d_out, 0, (size_t)2 * N * HDIM * sizeof(float), stream);

  kmsg<<<512, 256, 0, stream>>>(x, pos, pe, eidx, msg_w1, msg_b1, msg_w2, msg_b2, out_upd, E);
  kpos<<<512, 256, 0, stream>>>(pos, pe, eidx, mpos_w1, mpos_b1, mpos_w2, mpos_b2, out_upe, E);
  knode_upd<<<512, 256, 0, stream>>>(x, pe, out_upd, upd_w1, upd_b1, upd_w2, upd_b2, out_upd, N);
  knode_upe<<<768, 256, 0, stream>>>(pe, out_upe, upe_w1, upe_b1, upe_w2, upe_b2, out_upe, N);
}

// Round 3
// 622.737 us; speedup vs baseline: 3.0428x; 2.9971x over previous
//
#include <hip/hip_runtime.h>
#include <math.h>

#define HDIM 64
#define HF4  16

typedef __attribute__((ext_vector_type(8))) short short8;
typedef __attribute__((ext_vector_type(4))) float floatx4;
typedef unsigned short ushort_t;

#define MFMA16(a, b, c) __builtin_amdgcn_mfma_f32_16x16x32_bf16(a, b, c, 0, 0, 0)

__device__ __forceinline__ ushort_t f2bf(float f) {
  union { float f; unsigned u; } v; v.f = f;
  unsigned u = v.u;
  return (ushort_t)((u + 0x7FFFu + ((u >> 16) & 1u)) >> 16);
}

__device__ __forceinline__ float silu1(float v) { return __fdividef(v, 1.0f + __expf(-v)); }
__device__ __forceinline__ float tanh1(float v) {
  float t = __expf(2.0f * v);
  return 1.0f - __fdividef(2.0f, t + 1.0f);
}

__device__ __forceinline__ void fma4(float4& a, float s, const float4 w) {
  a.x = fmaf(s, w.x, a.x); a.y = fmaf(s, w.y, a.y);
  a.z = fmaf(s, w.z, a.z); a.w = fmaf(s, w.w, a.w);
}
__device__ __forceinline__ float4 silu4(float4 v) {
  return make_float4(silu1(v.x), silu1(v.y), silu1(v.z), silu1(v.w));
}
__device__ __forceinline__ float4 tanh4(float4 v) {
  return make_float4(tanh1(v.x), tanh1(v.y), tanh1(v.z), tanh1(v.w));
}

// ---------------- fp32 -> bf16 conversion (x, pe) ----------------
__global__ void kcvt(const float* __restrict__ s, ushort_t* __restrict__ d, int n) {
  int i = (blockIdx.x * 256 + threadIdx.x) * 8;
  if (i < n) {
    float4 a = *(const float4*)(s + i);
    float4 b = *(const float4*)(s + i + 4);
    union { ushort_t u[8]; uint4 v; } r;
    r.u[0] = f2bf(a.x); r.u[1] = f2bf(a.y); r.u[2] = f2bf(a.z); r.u[3] = f2bf(a.w);
    r.u[4] = f2bf(b.x); r.u[5] = f2bf(b.y); r.u[6] = f2bf(b.z); r.u[7] = f2bf(b.w);
    *(uint4*)(d + i) = r.v;
  }
}

// ================= edge kernel: message MLP via MFMA =================
// state = [x_s, pe_s, x_r, pe_r, dist] (K=257). Wave tile: 64 edges x 64 out.
__global__ __launch_bounds__(256, 2) void kmsg(
    const ushort_t* __restrict__ xb, const ushort_t* __restrict__ peb,
    const float* __restrict__ pos, const int* __restrict__ idx32,
    const float* __restrict__ w1, const float* __restrict__ b1,
    const float* __restrict__ w2, const float* __restrict__ b2,
    float* __restrict__ aggr, int E) {
  __shared__ ushort_t w1b[16384];          // 32 KB, [ks(8)][quad(4)][n(64)][j(8)]
  __shared__ ushort_t w2b[4096];           // 8 KB,  [ks(2)][quad(4)][n(64)][j(8)]
  __shared__ ushort_t hmat[4][4608];       // per-wave 64x72 bf16 (36.9 KB total)
  __shared__ int   srow[4][64];
  __shared__ int   rrow[4][64];
  __shared__ float ddv[4][64];
  __shared__ float cb1[64], cb2[64], wdv[64];

  // stage weights (bf16, B-fragment layout) once per block
  for (int i = threadIdx.x; i < 257 * 64; i += 256) {
    int k = i >> 6, n = i & 63; float v = w1[i];
    if (k < 256) w1b[(((k >> 5) * 4 + ((k >> 3) & 3)) * 64 + n) * 8 + (k & 7)] = f2bf(v);
    else wdv[n] = v;                       // dist row stays fp32
  }
  for (int i = threadIdx.x; i < 64 * 64; i += 256) {
    int k = i >> 6, n = i & 63;
    w2b[(((k >> 5) * 4 + ((k >> 3) & 3)) * 64 + n) * 8 + (k & 7)] = f2bf(w2[i]);
  }
  if (threadIdx.x < 64) { cb1[threadIdx.x] = b1[threadIdx.x]; cb2[threadIdx.x] = b2[threadIdx.x]; }
  __syncthreads();

  const int lane = threadIdx.x & 63;
  const int wv   = threadIdx.x >> 6;
  const int n15  = lane & 15;
  const int quad = lane >> 4;
  const bool is64 = (idx32[1] == 0) & (idx32[3] == 0) & (idx32[5] == 0) & (idx32[7] == 0);
  const int m = is64 ? 2 : 1;
  const int gw = blockIdx.x * 4 + wv;

  for (int base = gw * 64; base < E; base += gridDim.x * 256) {
    // stage this wave's 64 edges (intra-wave LDS: DS pipe is in-order per wave)
    {
      int e = base + lane, ec = min(e, E - 1);
      int s = idx32[(size_t)m * ec], r = idx32[(size_t)m * (E + ec)];
      srow[wv][lane] = s; rrow[wv][lane] = r;
      float dx = pos[3 * s + 0] - pos[3 * r + 0];
      float dy = pos[3 * s + 1] - pos[3 * r + 1];
      float dz = pos[3 * s + 2] - pos[3 * r + 2];
      ddv[wv][lane] = sqrtf(dx * dx + dy * dy + dz * dz);
    }
    int sm[4], rm[4];
#pragma unroll
    for (int mt = 0; mt < 4; ++mt) {
      sm[mt] = srow[wv][mt * 16 + n15];
      rm[mt] = rrow[wv][mt * 16 + n15];
    }

    floatx4 acc[4][4];
#pragma unroll
    for (int mt = 0; mt < 4; ++mt)
#pragma unroll
      for (int reg = 0; reg < 4; ++reg) {
        float dd = ddv[wv][mt * 16 + quad * 4 + reg];
#pragma unroll
        for (int nt = 0; nt < 4; ++nt)
          acc[mt][nt][reg] = cb1[nt * 16 + n15] + dd * wdv[nt * 16 + n15];
      }

    // layer 1: K=256 in 8 steps of 32
#pragma unroll
    for (int ks = 0; ks < 8; ++ks) {
      const int seg = ks >> 1, half = ks & 1;
      const ushort_t* sb = (seg == 0 || seg == 2) ? xb : peb;
      short8 B[4];
#pragma unroll
      for (int nt = 0; nt < 4; ++nt)
        B[nt] = *(const short8*)&w1b[((ks * 4 + quad) * 64 + nt * 16 + n15) * 8];
#pragma unroll
      for (int mt = 0; mt < 4; ++mt) {
        int row = (seg < 2) ? sm[mt] : rm[mt];
        short8 A = *(const short8*)(sb + (size_t)row * 64 + half * 32 + quad * 8);
#pragma unroll
        for (int nt = 0; nt < 4; ++nt)
          acc[mt][nt] = MFMA16(A, B[nt], acc[mt][nt]);
      }
    }

    // epilogue 1: silu -> bf16 h-matrix (A-layout round-trip via LDS)
#pragma unroll
    for (int mt = 0; mt < 4; ++mt)
#pragma unroll
      for (int nt = 0; nt < 4; ++nt)
#pragma unroll
        for (int reg = 0; reg < 4; ++reg)
          hmat[wv][(mt * 16 + quad * 4 + reg) * 72 + nt * 16 + n15] =
              f2bf(silu1(acc[mt][nt][reg]));

    // layer 2: K=64 in 2 steps
    floatx4 o[4][4];
#pragma unroll
    for (int mt = 0; mt < 4; ++mt)
#pragma unroll
      for (int nt = 0; nt < 4; ++nt) {
        float bv = cb2[nt * 16 + n15];
#pragma unroll
        for (int reg = 0; reg < 4; ++reg) o[mt][nt][reg] = bv;
      }
#pragma unroll
    for (int ks = 0; ks < 2; ++ks) {
      short8 B[4];
#pragma unroll
      for (int nt = 0; nt < 4; ++nt)
        B[nt] = *(const short8*)&w2b[((ks * 4 + quad) * 64 + nt * 16 + n15) * 8];
#pragma unroll
      for (int mt = 0; mt < 4; ++mt) {
        short8 A = *(const short8*)&hmat[wv][(mt * 16 + n15) * 72 + ks * 32 + quad * 8];
#pragma unroll
        for (int nt = 0; nt < 4; ++nt)
          o[mt][nt] = MFMA16(A, B[nt], o[mt][nt]);
      }
    }

    // epilogue 2: silu -> atomic scatter-add to aggr
#pragma unroll
    for (int mt = 0; mt < 4; ++mt)
#pragma unroll
      for (int reg = 0; reg < 4; ++reg) {
        const int el = mt * 16 + quad * 4 + reg;
        const int e  = base + el;
        if (e < E) {
          const int rnode = rrow[wv][el];
          float* t = aggr + (size_t)rnode * 64 + n15;
#pragma unroll
          for (int nt = 0; nt < 4; ++nt)
            unsafeAtomicAdd(t + nt * 16, silu1(o[mt][nt][reg]));
        }
      }
  }
}

// ================= edge kernel: positional MLP via MFMA =================
// state = [pe_s, pe_r, dist] (K=129), tanh activations.
__global__ __launch_bounds__(256, 2) void kpos(
    const ushort_t* __restrict__ peb,
    const float* __restrict__ pos, const int* __restrict__ idx32,
    const float* __restrict__ w1, const float* __restrict__ b1,
    const float* __restrict__ w2, const float* __restrict__ b2,
    float* __restrict__ aggrp, int E) {
  __shared__ ushort_t w1b[8192];           // 16 KB, ks(4)
  __shared__ ushort_t w2b[4096];           // 8 KB
  __shared__ ushort_t hmat[4][4608];
  __shared__ int   srow[4][64];
  __shared__ int   rrow[4][64];
  __shared__ float ddv[4][64];
  __shared__ float cb1[64], cb2[64], wdv[64];

  for (int i = threadIdx.x; i < 129 * 64; i += 256) {
    int k = i >> 6, n = i & 63; float v = w1[i];
    if (k < 128) w1b[(((k >> 5) * 4 + ((k >> 3) & 3)) * 64 + n) * 8 + (k & 7)] = f2bf(v);
    else wdv[n] = v;
  }
  for (int i = threadIdx.x; i < 64 * 64; i += 256) {
    int k = i >> 6, n = i & 63;
    w2b[(((k >> 5) * 4 + ((k >> 3) & 3)) * 64 + n) * 8 + (k & 7)] = f2bf(w2[i]);
  }
  if (threadIdx.x < 64) { cb1[threadIdx.x] = b1[threadIdx.x]; cb2[threadIdx.x] = b2[threadIdx.x]; }
  __syncthreads();

  const int lane = threadIdx.x & 63;
  const int wv   = threadIdx.x >> 6;
  const int n15  = lane & 15;
  const int quad = lane >> 4;
  const bool is64 = (idx32[1] == 0) & (idx32[3] == 0) & (idx32[5] == 0) & (idx32[7] == 0);
  const int m = is64 ? 2 : 1;
  const int gw = blockIdx.x * 4 + wv;

  for (int base = gw * 64; base < E; base += gridDim.x * 256) {
    {
      int e = base + lane, ec = min(e, E - 1);
      int s = idx32[(size_t)m * ec], r = idx32[(size_t)m * (E + ec)];
      srow[wv][lane] = s; rrow[wv][lane] = r;
      float dx = pos[3 * s + 0] - pos[3 * r + 0];
      float dy = pos[3 * s + 1] - pos[3 * r + 1];
      float dz = pos[3 * s + 2] - pos[3 * r + 2];
      ddv[wv][lane] = sqrtf(dx * dx + dy * dy + dz * dz);
    }
    int sm[4], rm[4];
#pragma unroll
    for (int mt = 0; mt < 4; ++mt) {
      sm[mt] = srow[wv][mt * 16 + n15];
      rm[mt] = rrow[wv][mt * 16 + n15];
    }

    floatx4 acc[4][4];
#pragma unroll
    for (int mt = 0; mt < 4; ++mt)
#pragma unroll
      for (int reg = 0; reg < 4; ++reg) {
        float dd = ddv[wv][mt * 16 + quad * 4 + reg];
#pragma unroll
        for (int nt = 0; nt < 4; ++nt)
          acc[mt][nt][reg] = cb1[nt * 16 + n15] + dd * wdv[nt * 16 + n15];
      }

#pragma unroll
    for (int ks = 0; ks < 4; ++ks) {
      const int seg = ks >> 1, half = ks & 1;
      short8 B[4];
#pragma unroll
      for (int nt = 0; nt < 4; ++nt)
        B[nt] = *(const short8*)&w1b[((ks * 4 + quad) * 64 + nt * 16 + n15) * 8];
#pragma unroll
      for (int mt = 0; mt < 4; ++mt) {
        int row = (seg == 0) ? sm[mt] : rm[mt];
        short8 A = *(const short8*)(peb + (size_t)row * 64 + half * 32 + quad * 8);
#pragma unroll
        for (int nt = 0; nt < 4; ++nt)
          acc[mt][nt] = MFMA16(A, B[nt], acc[mt][nt]);
      }
    }

#pragma unroll
    for (int mt = 0; mt < 4; ++mt)
#pragma unroll
      for (int nt = 0; nt < 4; ++nt)
#pragma unroll
        for (int reg = 0; reg < 4; ++reg)
          hmat[wv][(mt * 16 + quad * 4 + reg) * 72 + nt * 16 + n15] =
              f2bf(tanh1(acc[mt][nt][reg]));

    floatx4 o[4][4];
#pragma unroll
    for (int mt = 0; mt < 4; ++mt)
#pragma unroll
      for (int nt = 0; nt < 4; ++nt) {
        float bv = cb2[nt * 16 + n15];
#pragma unroll
        for (int reg = 0; reg < 4; ++reg) o[mt][nt][reg] = bv;
      }
#pragma unroll
    for (int ks = 0; ks < 2; ++ks) {
      short8 B[4];
#pragma unroll
      for (int nt = 0; nt < 4; ++nt)
        B[nt] = *(const short8*)&w2b[((ks * 4 + quad) * 64 + nt * 16 + n15) * 8];
#pragma unroll
      for (int mt = 0; mt < 4; ++mt) {
        short8 A = *(const short8*)&hmat[wv][(mt * 16 + n15) * 72 + ks * 32 + quad * 8];
#pragma unroll
        for (int nt = 0; nt < 4; ++nt)
          o[mt][nt] = MFMA16(A, B[nt], o[mt][nt]);
      }
    }

#pragma unroll
    for (int mt = 0; mt < 4; ++mt)
#pragma unroll
      for (int reg = 0; reg < 4; ++reg) {
        const int el = mt * 16 + quad * 4 + reg;
        const int e  = base + el;
        if (e < E) {
          const int rnode = rrow[wv][el];
          float* t = aggrp + (size_t)rnode * 64 + n15;
#pragma unroll
          for (int nt = 0; nt < 4; ++nt)
            unsafeAtomicAdd(t + nt * 16, tanh1(o[mt][nt][reg]));
        }
      }
  }
}

// ---------------- fp32 node kernels (unchanged structure) ----------------
__device__ __forceinline__ void seg64(float4& a0, float4& a1,
                                      const float* p0, const float* p1,
                                      const float4* wbase, int fg) {
#pragma unroll 4
  for (int kc = 0; kc < 16; ++kc) {
    float4 s0 = ((const float4*)p0)[kc];
    float4 s1 = ((const float4*)p1)[kc];
    float4 w0 = wbase[(4 * kc + 0) * HF4 + fg];
    float4 w1 = wbase[(4 * kc + 1) * HF4 + fg];
    float4 w2 = wbase[(4 * kc + 2) * HF4 + fg];
    float4 w3 = wbase[(4 * kc + 3) * HF4 + fg];
    fma4(a0, s0.x, w0); fma4(a0, s0.y, w1); fma4(a0, s0.z, w2); fma4(a0, s0.w, w3);
    fma4(a1, s1.x, w0); fma4(a1, s1.y, w1); fma4(a1, s1.z, w2); fma4(a1, s1.w, w3);
  }
}

__device__ __forceinline__ void layer2acc(float4& o0, float4& o1,
                                          const float* h0p, const float* h1p,
                                          const float4* w2v, int fg) {
#pragma unroll 4
  for (int jc = 0; jc < 16; ++jc) {
    float4 h0 = ((const float4*)h0p)[jc];
    float4 h1 = ((const float4*)h1p)[jc];
    float4 q0 = w2v[(4 * jc + 0) * HF4 + fg];
    float4 q1 = w2v[(4 * jc + 1) * HF4 + fg];
    float4 q2 = w2v[(4 * jc + 2) * HF4 + fg];
    float4 q3 = w2v[(4 * jc + 3) * HF4 + fg];
    fma4(o0, h0.x, q0); fma4(o0, h0.y, q1); fma4(o0, h0.z, q2); fma4(o0, h0.w, q3);
    fma4(o1, h1.x, q0); fma4(o1, h1.y, q1); fma4(o1, h1.z, q2); fma4(o1, h1.w, q3);
  }
}

__global__ __launch_bounds__(256, 2) void knode_upd(
    const float* __restrict__ x, const float* __restrict__ pe,
    const float* aggr,
    const float* __restrict__ w1, const float* __restrict__ b1,
    const float* __restrict__ w2, const float* __restrict__ b2,
    float* outp, int N) {
  __shared__ float4 lw1[192 * HF4];
  __shared__ __align__(16) float lh[4][8][68];

  const float4* w1v = (const float4*)w1;
  for (int i = threadIdx.x; i < 192 * HF4; i += 256) lw1[i] = w1v[i];
  __syncthreads();

  const int lane = threadIdx.x & 63;
  const int wv   = threadIdx.x >> 6;
  const int fg   = lane & 15;
  const int eq   = lane >> 4;
  const int gw   = blockIdx.x * 4 + wv;
  const int stride = gridDim.x * 4 * 8;

  const float4 bias1 = ((const float4*)b1)[fg];
  const float4 bias2 = ((const float4*)b2)[fg];
  const float4* w2v  = (const float4*)w2;

  for (int base = gw * 8; base < N; base += stride) {
    const int n0 = base + eq, n1 = base + eq + 4;
    const int n0c = min(n0, N - 1), n1c = min(n1, N - 1);

    float4 a0 = bias1, a1 = bias1;
    seg64(a0, a1, x    + (size_t)n0c * HDIM, x    + (size_t)n1c * HDIM, lw1,             fg);
    seg64(a0, a1, pe   + (size_t)n0c * HDIM, pe   + (size_t)n1c * HDIM, lw1 + 64 * HF4,  fg);
    seg64(a0, a1, aggr + (size_t)n0c * HDIM, aggr + (size_t)n1c * HDIM, lw1 + 128 * HF4, fg);
    a0 = silu4(a0); a1 = silu4(a1);

    *(float4*)&lh[wv][eq][4 * fg]     = a0;
    *(float4*)&lh[wv][eq + 4][4 * fg] = a1;

    float4 o0 = bias2, o1 = bias2;
    layer2acc(o0, o1, &lh[wv][eq][0], &lh[wv][eq + 4][0], w2v, fg);

    if (n0 < N) *(float4*)(outp + (size_t)n0 * HDIM + 4 * fg) = o0;
    if (n1 < N) *(float4*)(outp + (size_t)n1 * HDIM + 4 * fg) = o1;
  }
}

__global__ __launch_bounds__(256, 2) void knode_upe(
    const float* __restrict__ pe,
    const float* aggrp,
    const float* __restrict__ w1, const float* __restrict__ b1,
    const float* __restrict__ w2, const float* __restrict__ b2,
    float* outp, int N) {
  __shared__ float4 lw1[128 * HF4];
  __shared__ __align__(16) float lh[4][8][68];

  const float4* w1v = (const float4*)w1;
  for (int i = threadIdx.x; i < 128 * HF4; i += 256) lw1[i] = w1v[i];
  __syncthreads();

  const int lane = threadIdx.x & 63;
  const int wv   = threadIdx.x >> 6;
  const int fg   = lane & 15;
  const int eq   = lane >> 4;
  const int gw   = blockIdx.x * 4 + wv;
  const int stride = gridDim.x * 4 * 8;

  const float4 bias1 = ((const float4*)b1)[fg];
  const float4 bias2 = ((const float4*)b2)[fg];
  const float4* w2v  = (const float4*)w2;

  for (int base = gw * 8; base < N; base += stride) {
    const int n0 = base + eq, n1 = base + eq + 4;
    const int n0c = min(n0, N - 1), n1c = min(n1, N - 1);

    float4 a0 = bias1, a1 = bias1;
    seg64(a0, a1, pe    + (size_t)n0c * HDIM, pe    + (size_t)n1c * HDIM, lw1,            fg);
    seg64(a0, a1, aggrp + (size_t)n0c * HDIM, aggrp + (size_t)n1c * HDIM, lw1 + 64 * HF4, fg);
    a0 = tanh4(a0); a1 = tanh4(a1);

    *(float4*)&lh[wv][eq][4 * fg]     = a0;
    *(float4*)&lh[wv][eq + 4][4 * fg] = a1;

    float4 o0 = bias2, o1 = bias2;
    layer2acc(o0, o1, &lh[wv][eq][0], &lh[wv][eq + 4][0], w2v, fg);
    o0 = tanh4(o0); o1 = tanh4(o1);

    if (n0 < N) *(float4*)(outp + (size_t)n0 * HDIM + 4 * fg) = o0;
    if (n1 < N) *(float4*)(outp + (size_t)n1 * HDIM + 4 * fg) = o1;
  }
}

extern "C" void kernel_launch(void* const* d_in, const int* in_sizes, int n_in,
                              void* d_out, int out_size, void* d_ws, size_t ws_size,
                              hipStream_t stream) {
  const float* x    = (const float*)d_in[0];
  const float* pos  = (const float*)d_in[1];
  const float* pe   = (const float*)d_in[2];
  const int*   eidx = (const int*)d_in[3];
  const float* msg_w1  = (const float*)d_in[4];
  const float* msg_b1  = (const float*)d_in[5];
  const float* msg_w2  = (const float*)d_in[6];
  const float* msg_b2  = (const float*)d_in[7];
  const float* mpos_w1 = (const float*)d_in[8];
  const float* mpos_b1 = (const float*)d_in[9];
  const float* mpos_w2 = (const float*)d_in[10];
  const float* mpos_b2 = (const float*)d_in[11];
  const float* upd_w1  = (const float*)d_in[12];
  const float* upd_b1  = (const float*)d_in[13];
  const float* upd_w2  = (const float*)d_in[14];
  const float* upd_b2  = (const float*)d_in[15];
  const float* upe_w1  = (const float*)d_in[16];
  const float* upe_b1  = (const float*)d_in[17];
  const float* upe_w2  = (const float*)d_in[18];
  const float* upe_b2  = (const float*)d_in[19];

  const int N = in_sizes[0] / HDIM;
  const int E = in_sizes[3] / 2;

  float* out_upd = (float*)d_out;                 // aggr accumulator, then update out
  float* out_upe = out_upd + (size_t)N * HDIM;    // aggr_pos accumulator, then update_pe out

  ushort_t* xb  = (ushort_t*)d_ws;                // bf16 copies of x, pe in workspace
  ushort_t* peb = xb + (size_t)N * HDIM;

  hipMemsetAsync(d_out, 0, (size_t)2 * N * HDIM * sizeof(float), stream);

  const int ncv = N * HDIM;
  kcvt<<<(ncv / 8 + 255) / 256, 256, 0, stream>>>(x,  xb,  ncv);
  kcvt<<<(ncv / 8 + 255) / 256, 256, 0, stream>>>(pe, peb, ncv);

  kmsg<<<625, 256, 0, stream>>>(xb, peb, pos, eidx, msg_w1, msg_b1, msg_w2, msg_b2, out_upd, E);
  kpos<<<625, 256, 0, stream>>>(peb, pos, eidx, mpos_w1, mpos_b1, mpos_w2, mpos_b2, out_upe, E);
  knode_upd<<<512, 256, 0, stream>>>(x, pe, out_upd, upd_w1, upd_b1, upd_w2, upd_b2, out_upd, N);
  knode_upe<<<768, 256, 0, stream>>>(pe, out_upe, upe_w1, upe_b1, upe_w2, upe_b2, out_upe, N);
}